// Round 4
// baseline (269.434 us; speedup 1.0000x reference)
//
#include <hip/hip_runtime.h>
#include <cstdint>
#include <cstddef>

typedef __bf16 bf16_t;
typedef __bf16 bf16x8 __attribute__((ext_vector_type(8)));
typedef __bf16 bf16x4v __attribute__((ext_vector_type(4)));
typedef float f32x16 __attribute__((ext_vector_type(16)));

static __device__ __forceinline__ f32x16 mfma32(bf16x8 a, bf16x8 b, f32x16 c) {
  return __builtin_amdgcn_mfma_f32_32x32x16_bf16(a, b, c, 0, 0, 0);
}

// Direct global->LDS DMA, 16B per lane. LDS dest is wave-uniform base + lane*16;
// global src is per-lane (swizzle baked into the gather address).
static __device__ __forceinline__ void gld_lds16(const void* g, void* l) {
  __builtin_amdgcn_global_load_lds(
      (const __attribute__((address_space(1))) unsigned int*)g,
      (__attribute__((address_space(3))) unsigned int*)l, 16, 0, 0);
}

#define CEXP_CONST 0.12754582f  // (1/sqrt(128)) * log2(e)

// ---------------------------------------------------------------------------
// Workspace layout (bytes):
//   [0, 768K)        Wt    bf16 [3][128][1024]
//   [1M, 9M)         Qp    bf16 [8][4096][128]
//   [9M, 17M)        Kp    bf16 [8][4096][128]
//   [17M, 25M)       Vt    bf16 [8][128][4096]
//   [32M, 64M)       Opart f32  [2*256][128][128]
//   [64M, +256K)     Mpart f32  [2*256*128]
//   [64M+256K,+256K) Lpart f32  [2*256*128]
// ---------------------------------------------------------------------------

__global__ void wt_kernel(const float* __restrict__ Wq, const float* __restrict__ Wk,
                          const float* __restrict__ Wv, bf16_t* __restrict__ Wt) {
  int t = blockIdx.x * 256 + threadIdx.x;
  int tensor = t >> 17;
  int r = t & 131071;
  int kk = r >> 7, n = r & 127;
  const float* W = tensor == 0 ? Wq : (tensor == 1 ? Wk : Wv);
  Wt[(size_t)tensor * 131072 + (size_t)n * 1024 + kk] = (bf16_t)W[(size_t)kk * 128 + n];
}

// X[32768,1024]f32 @ W[1024,128] -> bf16. Barrier-free: per-lane A fragments
// direct from global (row = w*32+l31, k = kt*16+h*8), W fragments from L1/L2.
// LDS used only for the coalesced-store epilogue.
// ty: 0=Q, 1=K (row-major out), 2=V (transposed out).
__global__ __launch_bounds__(256, 3) void proj_kernel(
    const float* __restrict__ xq, const float* __restrict__ xk, const float* __restrict__ xv,
    const bf16_t* __restrict__ WtAll,
    bf16_t* __restrict__ Qp, bf16_t* __restrict__ Kp, bf16_t* __restrict__ Vt) {
  __shared__ __align__(16) char smc[33792];  // 128 rows x 264B (Qp/Kp) | 32KB (Vt)
  const int tid = threadIdx.x;
  const int ty = blockIdx.y;
  const int bm = blockIdx.x;
  const float* X = (ty == 0) ? xq : (ty == 1) ? xk : xv;
  const bf16_t* W = WtAll + (size_t)ty * 131072;
  const int lane = tid & 63;
  const int w = tid >> 6;
  const int l31 = lane & 31, h = lane >> 5;

  f32x16 acc[4];
#pragma unroll
  for (int nf = 0; nf < 4; ++nf)
#pragma unroll
    for (int r = 0; r < 16; ++r) acc[nf][r] = 0.0f;

  const float* ap = X + (size_t)(bm * 128 + w * 32 + l31) * 1024 + h * 8;
  const bf16_t* wp = W + (size_t)l31 * 1024 + h * 8;

#pragma unroll 4
  for (int kt = 0; kt < 64; ++kt) {
    float4 a0 = *(const float4*)(ap + kt * 16);
    float4 a1 = *(const float4*)(ap + kt * 16 + 4);
    bf16x8 af;
    af[0] = (bf16_t)a0.x; af[1] = (bf16_t)a0.y; af[2] = (bf16_t)a0.z; af[3] = (bf16_t)a0.w;
    af[4] = (bf16_t)a1.x; af[5] = (bf16_t)a1.y; af[6] = (bf16_t)a1.z; af[7] = (bf16_t)a1.w;
#pragma unroll
    for (int nf = 0; nf < 4; ++nf) {
      bf16x8 wf = *(const bf16x8*)(wp + nf * 32768 + kt * 16);
      acc[nf] = mfma32(af, wf, acc[nf]);
    }
  }

  if (ty < 2) {
    // Stage C-tile in LDS (row stride 264B vs bank aliasing), then coalesced uint4 out.
    constexpr int RS = 264;
#pragma unroll
    for (int nf = 0; nf < 4; ++nf)
#pragma unroll
      for (int r = 0; r < 16; ++r) {
        int rowL = w * 32 + (r & 3) + 8 * (r >> 2) + 4 * h;
        *(bf16_t*)(smc + rowL * RS + (nf * 32 + l31) * 2) = (bf16_t)acc[nf][r];
      }
    __syncthreads();
    bf16_t* O = (ty == 0) ? Qp : Kp;
    char* obase = (char*)(O + (size_t)(bm * 128) * 128);
#pragma unroll
    for (int ii = 0; ii < 8; ++ii) {
      int g = ii * 256 + tid;          // 2048 x 16B chunks
      int rr = g >> 4, ch = g & 15;
      uint4 vv = *(const uint4*)(smc + rr * RS + ch * 16);
      *(uint4*)(obase + rr * 256 + ch * 16) = vv;
    }
  } else {
    // transpose 128x128 tile through LDS, write Vt[b][n][m] coalesced
#pragma unroll
    for (int nf = 0; nf < 4; ++nf)
#pragma unroll
      for (int rg = 0; rg < 4; ++rg) {
        int n = nf * 32 + l31;
        bf16x4v bv;
#pragma unroll
        for (int j = 0; j < 4; ++j) bv[j] = (bf16_t)acc[nf][rg * 4 + j];
        int byt = n * 256 + (((4 * w + rg) ^ (n & 7)) << 4) + 8 * h;
        *(uint2*)(smc + byt) = __builtin_bit_cast(uint2, bv);
      }
    __syncthreads();
    const int bb = bm >> 5;
    const int r0v = (bm & 31) * 128;
#pragma unroll
    for (int i = 0; i < 8; ++i) {
      int c = tid + 256 * i;
      int n = c >> 4, sl = c & 15;
      uint4 vv = *(const uint4*)(smc + n * 256 + ((sl ^ (n & 7)) << 4));
      *(uint4*)(Vt + (size_t)(bb * 128 + n) * 4096 + r0v + sl * 8) = vv;
    }
  }
}

// Build PV A-fragment (j = B0-half of one f32x16 S block, 16 j's) in-register:
// 4x v_cvt_pk_bf16_f32 + 4x shfl_xor(32) + selects. No LDS.
template <int B0>
static __device__ __forceinline__ bf16x8 build_pf(const f32x16& s, int h) {
  unsigned c0, c1, c2, c3;
  asm("v_cvt_pk_bf16_f32 %0, %1, %2" : "=v"(c0) : "v"(s[B0 + 0]), "v"(s[B0 + 1]));
  asm("v_cvt_pk_bf16_f32 %0, %1, %2" : "=v"(c1) : "v"(s[B0 + 2]), "v"(s[B0 + 3]));
  asm("v_cvt_pk_bf16_f32 %0, %1, %2" : "=v"(c2) : "v"(s[B0 + 4]), "v"(s[B0 + 5]));
  asm("v_cvt_pk_bf16_f32 %0, %1, %2" : "=v"(c3) : "v"(s[B0 + 6]), "v"(s[B0 + 7]));
  unsigned x0 = (unsigned)__shfl_xor((int)c0, 32);
  unsigned x1 = (unsigned)__shfl_xor((int)c1, 32);
  unsigned x2 = (unsigned)__shfl_xor((int)c2, 32);
  unsigned x3 = (unsigned)__shfl_xor((int)c3, 32);
  uint4 u;
  u.x = h ? x2 : c0;
  u.y = h ? x3 : c1;
  u.z = h ? c2 : x0;
  u.w = h ? c3 : x1;
  return __builtin_bit_cast(bf16x8, u);
}

// Flash attention. 256 threads (4 waves), QBLK=128 (32 q-rows/wave), KVBLK=64.
// K/V double-buffered in LDS via global_load_lds with gather-side swizzle;
// counted vmcnt(8) pipeline (never 0 in main loop).
// grid.x = 256*SPLIT: b = bid&7 (XCD affinity), qt = (bid>>3)&31, s = bid>>8.
template <int SPLIT>
__global__ __launch_bounds__(256, 2) void attn_kernel(
    const bf16_t* __restrict__ Qp, const bf16_t* __restrict__ Kp,
    const bf16_t* __restrict__ Vt, float* __restrict__ out,
    float* __restrict__ Opart, float* __restrict__ Mpart, float* __restrict__ Lpart) {
  __shared__ __align__(16) char smc[65536];  // 2 x (K 16K | V 16K)
  const int tid = threadIdx.x;
  const int lane = tid & 63, w = tid >> 6;
  const int l31 = lane & 31, h = lane >> 5;
  const int bid = blockIdx.x;
  const int b = bid & 7;
  const int qt = (bid >> 3) & 31;
  const int s = bid >> 8;
  const int NT = 64 / SPLIT;
  const float CEXP = CEXP_CONST;
  const int qbase = qt * 128 + w * 32;
  const int sw0 = (l31 ^ (l31 >> 3)) & 7;  // K-row swizzle for row l31
  const int sw1 = sw0 ^ 4;                 // for row l31+32

  // Q fragments: lane holds q-row l31, d = db*16 + h*8 + 0..8
  bf16x8 qf[8];
  const bf16_t* qrow = Qp + (size_t)(b * 4096 + qbase + l31) * 128 + h * 8;
#pragma unroll
  for (int db = 0; db < 8; ++db) qf[db] = *(const bf16x8*)(qrow + db * 16);

  // V-row swizzle for rows d = nf*32 + l31
  int swv[4];
#pragma unroll
  for (int nf = 0; nf < 4; ++nf) swv[nf] = (l31 & 7) ^ ((4 * nf + (l31 >> 3)) & 7);

  // Gather offsets (swizzle on the global side; LDS dest linear).
  const int rl = lane >> 4, slK = lane & 15;
  const int dl = lane >> 3, slV = lane & 7;
  int koff[4], voff[4];
#pragma unroll
  for (int i = 0; i < 4; ++i) {
    int r = w * 16 + i * 4 + rl;
    int swr = (r ^ (r >> 3)) & 7;
    koff[i] = r * 256 + (((slK & 8) | ((slK & 7) ^ swr)) << 4);
    int d = w * 32 + i * 8 + dl;
    int swd = (d ^ (d >> 3)) & 7;
    voff[i] = d * 8192 + ((slV ^ swd) << 4);
  }
  const char* kpb = (const char*)Kp + (size_t)b * 1048576 + (size_t)s * NT * 16384;
  const char* vpb = (const char*)Vt + (size_t)b * 1048576 + (size_t)s * NT * 128;

  f32x16 oacc[4];
#pragma unroll
  for (int nf = 0; nf < 4; ++nf)
#pragma unroll
    for (int r = 0; r < 16; ++r) oacc[nf][r] = 0.0f;
  float m_run = -3.0e38f, lacc = 0.0f;

  auto stage = [&](int tt, int bufb) {
    const char* kb = kpb + (size_t)tt * 16384;
    const char* vb = vpb + (size_t)tt * 128;
    char* lk = smc + bufb + w * 4096;
    char* lv = smc + bufb + 16384 + w * 4096;
#pragma unroll
    for (int i = 0; i < 4; ++i) {
      gld_lds16(kb + koff[i], lk + i * 1024);
      gld_lds16(vb + voff[i], lv + i * 1024);
    }
  };

  stage(0, 0);
  stage(1, 32768);

  for (int t = 0; t < NT; ++t) {
    asm volatile("s_waitcnt vmcnt(8)" ::: "memory");  // tile t landed; t+1 in flight
    __builtin_amdgcn_s_barrier();
    const char* kb = smc + (t & 1) * 32768;
    const char* vb = kb + 16384;

    // ---- S^T = mfma(K, Q): lane owns q-row l31 ----
    f32x16 s0, s1;
#pragma unroll
    for (int i = 0; i < 16; ++i) { s0[i] = 0.0f; s1[i] = 0.0f; }
    __builtin_amdgcn_s_setprio(1);
#pragma unroll
    for (int db = 0; db < 8; ++db) {
      const int q = 2 * db + h;
      bf16x8 k0 = *(const bf16x8*)(kb + l31 * 256 + (((q & 8) | ((q & 7) ^ sw0)) << 4));
      bf16x8 k1 = *(const bf16x8*)(kb + (32 + l31) * 256 + (((q & 8) | ((q & 7) ^ sw1)) << 4));
      s0 = mfma32(k0, qf[db], s0);
      s1 = mfma32(k1, qf[db], s1);
    }
    __builtin_amdgcn_s_setprio(0);

    // ---- online softmax (raw logits; scale folded into exp2) ----
    float tmax = fmaxf(s0[0], s1[0]);
#pragma unroll
    for (int i = 1; i < 16; ++i) tmax = fmaxf(tmax, fmaxf(s0[i], s1[i]));
    tmax = fmaxf(tmax, __shfl_xor(tmax, 32));
    if (__any(tmax > m_run + 62.0f)) {  // defer-max: p bounded by 2^7.9
      float mnew = fmaxf(m_run, tmax);
      float fac = exp2f((m_run - mnew) * CEXP);
      m_run = mnew;
      lacc *= fac;
#pragma unroll
      for (int r = 0; r < 16; ++r) {
        float fr = __shfl(fac, (r & 3) + 8 * (r >> 2) + 4 * h);
#pragma unroll
        for (int nf = 0; nf < 4; ++nf) oacc[nf][r] *= fr;
      }
    }
    const float mc = m_run * CEXP;
#pragma unroll
    for (int i = 0; i < 16; ++i) s0[i] = exp2f(fmaf(s0[i], CEXP, -mc));
#pragma unroll
    for (int i = 0; i < 16; ++i) s1[i] = exp2f(fmaf(s1[i], CEXP, -mc));
    float a0 = 0.f, a1 = 0.f, a2 = 0.f, a3 = 0.f;
#pragma unroll
    for (int i = 0; i < 16; i += 4) {
      a0 += s0[i] + s1[i];         a1 += s0[i + 1] + s1[i + 1];
      a2 += s0[i + 2] + s1[i + 2]; a3 += s0[i + 3] + s1[i + 3];
    }
    lacc += (a0 + a1) + (a2 + a3);

    // ---- PV: oacc += P[32q x 64j] @ V[64j x 128d], P built in-register ----
    __builtin_amdgcn_s_setprio(1);
    {
      bf16x8 pf = build_pf<0>(s0, h);
#pragma unroll
      for (int nf = 0; nf < 4; ++nf) {
        bf16x8 vf = *(const bf16x8*)(vb + (nf * 32 + l31) * 128 + (((0 + h) ^ swv[nf]) << 4));
        oacc[nf] = mfma32(pf, vf, oacc[nf]);
      }
    }
    {
      bf16x8 pf = build_pf<8>(s0, h);
#pragma unroll
      for (int nf = 0; nf < 4; ++nf) {
        bf16x8 vf = *(const bf16x8*)(vb + (nf * 32 + l31) * 128 + (((2 + h) ^ swv[nf]) << 4));
        oacc[nf] = mfma32(pf, vf, oacc[nf]);
      }
    }
    {
      bf16x8 pf = build_pf<0>(s1, h);
#pragma unroll
      for (int nf = 0; nf < 4; ++nf) {
        bf16x8 vf = *(const bf16x8*)(vb + (nf * 32 + l31) * 128 + (((4 + h) ^ swv[nf]) << 4));
        oacc[nf] = mfma32(pf, vf, oacc[nf]);
      }
    }
    {
      bf16x8 pf = build_pf<8>(s1, h);
#pragma unroll
      for (int nf = 0; nf < 4; ++nf) {
        bf16x8 vf = *(const bf16x8*)(vb + (nf * 32 + l31) * 128 + (((6 + h) ^ swv[nf]) << 4));
        oacc[nf] = mfma32(pf, vf, oacc[nf]);
      }
    }
    __builtin_amdgcn_s_setprio(0);

    __builtin_amdgcn_s_barrier();  // all waves done reading buf[t&1]
    stage((t + 2) & (NT - 1), (t & 1) * 32768);  // wrap keeps vmcnt count uniform
  }
  asm volatile("s_waitcnt vmcnt(0)" ::: "memory");  // drain wrap loads

  lacc += __shfl_xor(lacc, 32);
  if (SPLIT == 1) {
    const float inv = 1.0f / lacc;
    float* ob = out + (size_t)(b * 4096 + qbase) * 128;
#pragma unroll
    for (int r = 0; r < 16; ++r) {
      const int rowD = (r & 3) + 8 * (r >> 2) + 4 * h;
      float ir = __shfl(inv, rowD);
#pragma unroll
      for (int nf = 0; nf < 4; ++nf)
        ob[(size_t)rowD * 128 + nf * 32 + l31] = oacc[nf][r] * ir;
    }
  } else {
    const int pb = s * 256 + b * 32 + qt;
    if (lane < 32) {
      Mpart[pb * 128 + w * 32 + l31] = m_run;
      Lpart[pb * 128 + w * 32 + l31] = lacc;
    }
    float* ob = Opart + ((size_t)pb * 128 + w * 32) * 128;
#pragma unroll
    for (int r = 0; r < 16; ++r) {
      const int rowD = (r & 3) + 8 * (r >> 2) + 4 * h;
#pragma unroll
      for (int nf = 0; nf < 4; ++nf)
        ob[(size_t)rowD * 128 + nf * 32 + l31] = oacc[nf][r];
    }
  }
}

// Combine 2 split partials. grid 4096 x 256: 8 rows/block, 32 lanes/row (float4).
__global__ __launch_bounds__(256) void combine_kernel(
    const float* __restrict__ Opart, const float* __restrict__ Mpart,
    const float* __restrict__ Lpart, float* __restrict__ out) {
  const int g = blockIdx.x * 8 + (threadIdx.x >> 5);  // global q-row, 0..32767
  const int lane32 = threadIdx.x & 31;
  const int b = g >> 12;
  const int pos = g & 4095;
  const int qt = pos >> 7;
  const int row = pos & 127;
  const int i0 = (b * 32 + qt) * 128 + row;
  const int i1 = (256 + b * 32 + qt) * 128 + row;
  const float m0 = Mpart[i0], m1 = Mpart[i1];
  const float l0 = Lpart[i0], l1 = Lpart[i1];
  const float m = fmaxf(m0, m1);
  const float w0 = exp2f((m0 - m) * CEXP_CONST);
  const float w1 = exp2f((m1 - m) * CEXP_CONST);
  const float inv = 1.0f / (w0 * l0 + w1 * l1);
  const float4 o0 = *(const float4*)(Opart + (size_t)i0 * 128 + lane32 * 4);
  const float4 o1 = *(const float4*)(Opart + (size_t)i1 * 128 + lane32 * 4);
  float4 o;
  o.x = (w0 * o0.x + w1 * o1.x) * inv;
  o.y = (w0 * o0.y + w1 * o1.y) * inv;
  o.z = (w0 * o0.z + w1 * o1.z) * inv;
  o.w = (w0 * o0.w + w1 * o1.w) * inv;
  *(float4*)(out + (size_t)g * 128 + lane32 * 4) = o;
}

extern "C" void kernel_launch(void* const* d_in, const int* in_sizes, int n_in,
                              void* d_out, int out_size, void* d_ws, size_t ws_size,
                              hipStream_t stream) {
  const float* q  = (const float*)d_in[0];
  const float* k  = (const float*)d_in[1];
  const float* v  = (const float*)d_in[2];
  const float* Wq = (const float*)d_in[3];
  const float* Wk = (const float*)d_in[4];
  const float* Wv = (const float*)d_in[5];
  float* out = (float*)d_out;
  char* ws = (char*)d_ws;
  bf16_t* Wt = (bf16_t*)(ws);
  bf16_t* Qp = (bf16_t*)(ws + (size_t)(1u << 20));
  bf16_t* Kp = (bf16_t*)(ws + (size_t)(9u << 20));
  bf16_t* Vt = (bf16_t*)(ws + (size_t)(17u << 20));
  float* Opart = (float*)(ws + (size_t)(32u << 20));
  float* Mpart = (float*)(ws + (size_t)(64u << 20));
  float* Lpart = (float*)(ws + (size_t)(64u << 20) + (256u << 10));

  hipLaunchKernelGGL(wt_kernel, dim3(1536), dim3(256), 0, stream, Wq, Wk, Wv, Wt);
  hipLaunchKernelGGL(proj_kernel, dim3(256, 3), dim3(256), 0, stream, q, k, v, Wt, Qp, Kp, Vt);

  if (ws_size >= ((size_t)65 << 20)) {
    hipLaunchKernelGGL((attn_kernel<2>), dim3(512), dim3(256), 0, stream,
                       Qp, Kp, Vt, out, Opart, Mpart, Lpart);
    hipLaunchKernelGGL(combine_kernel, dim3(4096), dim3(256), 0, stream,
                       Opart, Mpart, Lpart, out);
  } else {
    hipLaunchKernelGGL((attn_kernel<1>), dim3(256), dim3(256), 0, stream,
                       Qp, Kp, Vt, out, Opart, Mpart, Lpart);
  }
}

// Round 5
// 214.358 us; speedup vs baseline: 1.2569x; 1.2569x over previous
//
#include <hip/hip_runtime.h>
#include <cstdint>
#include <cstddef>

typedef __bf16 bf16_t;
typedef __bf16 bf16x8 __attribute__((ext_vector_type(8)));
typedef __bf16 bf16x4v __attribute__((ext_vector_type(4)));
typedef float f32x16 __attribute__((ext_vector_type(16)));

static __device__ __forceinline__ f32x16 mfma32(bf16x8 a, bf16x8 b, f32x16 c) {
  return __builtin_amdgcn_mfma_f32_32x32x16_bf16(a, b, c, 0, 0, 0);
}

// Direct global->LDS DMA, 16B per lane. LDS dest is wave-uniform base + lane*16;
// global src is per-lane (swizzle baked into the gather address).
static __device__ __forceinline__ void gld_lds16(const void* g, void* l) {
  __builtin_amdgcn_global_load_lds(
      (const __attribute__((address_space(1))) unsigned int*)g,
      (__attribute__((address_space(3))) unsigned int*)l, 16, 0, 0);
}

#define CEXP_CONST 0.12754582f  // (1/sqrt(128)) * log2(e)

// ---------------------------------------------------------------------------
// Workspace layout (bytes):
//   [0, 768K)        Wt    bf16 [3][128][1024]
//   [1M, 9M)         Qp    bf16 [8][4096][128]
//   [9M, 17M)        Kp    bf16 [8][4096][128]
//   [17M, 25M)       Vt    bf16 [8][128][4096]
//   [32M, 64M)       Opart f32  [2*256][128][128]
//   [64M, +256K)     Mpart f32  [2*256*128]
//   [64M+256K,+256K) Lpart f32  [2*256*128]
// ---------------------------------------------------------------------------

__global__ void wt_kernel(const float* __restrict__ Wq, const float* __restrict__ Wk,
                          const float* __restrict__ Wv, bf16_t* __restrict__ Wt) {
  int t = blockIdx.x * 256 + threadIdx.x;
  int tensor = t >> 17;
  int r = t & 131071;
  int kk = r >> 7, n = r & 127;
  const float* W = tensor == 0 ? Wq : (tensor == 1 ? Wk : Wv);
  Wt[(size_t)tensor * 131072 + (size_t)n * 1024 + kk] = (bf16_t)W[(size_t)kk * 128 + n];
}

// X[32768,1024]f32 @ W[1024,128] -> bf16.
// A and W staged in LDS via global_load_lds (coalesced, swizzled-source),
// double-buffered with counted vmcnt(6). BK=32. 4 waves, BM=128.
// ty: 0=Q, 1=K (row-major out), 2=V (transposed out).
__global__ __launch_bounds__(256, 3) void proj_kernel(
    const float* __restrict__ xq, const float* __restrict__ xk, const float* __restrict__ xv,
    const bf16_t* __restrict__ WtAll,
    bf16_t* __restrict__ Qp, bf16_t* __restrict__ Kp, bf16_t* __restrict__ Vt) {
  // A dbuf: [0,32K) two 16KB buffers (128 rows x 128B, slot^=(row&7)).
  // W dbuf: [32K,48K) two 8KB buffers (128 n-rows x 64B, slot^=((n>>1)&3)).
  // Epilogue reuses [0,34K).
  __shared__ __align__(16) char smc[49152];
  const int tid = threadIdx.x;
  const int ty = blockIdx.y;
  const int bm = blockIdx.x;
  const float* X = (ty == 0) ? xq : (ty == 1) ? xk : xv;
  const bf16_t* W = WtAll + (size_t)ty * 131072;
  const int lane = tid & 63;
  const int w = tid >> 6;
  const int l31 = lane & 31, h = lane >> 5;
  const int asw = l31 & 7;            // A read swizzle (row = l31)
  f32x16 acc[4];
#pragma unroll
  for (int nf = 0; nf < 4; ++nf)
#pragma unroll
    for (int r = 0; r < 16; ++r) acc[nf][r] = 0.0f;

  // Stage source offsets (bytes), swizzle on the global side; LDS dest linear.
  // A: wave w stages rows w*32 + i*8 + (lane>>3), 16B slot lane&7 (of 8).
  int aoff[4];
#pragma unroll
  for (int i = 0; i < 4; ++i) {
    int r = w * 32 + i * 8 + (lane >> 3);
    aoff[i] = r * 4096 + (((lane & 7) ^ (r & 7)) << 4);
  }
  // W: wave w stages n-rows w*32 + j*16 + (lane>>2), 16B slot lane&3 (of 4).
  int woff[2];
#pragma unroll
  for (int j = 0; j < 2; ++j) {
    int n = w * 32 + j * 16 + (lane >> 2);
    woff[j] = n * 2048 + (((lane & 3) ^ ((n >> 1) & 3)) << 4);
  }
  const char* ag = (const char*)(X + (size_t)bm * 128 * 1024);
  const char* wg = (const char*)W;

  auto stage = [&](int t, int buf) {
    const char* at = ag + t * 128;   // +32 floats per k-tile
    const char* wt = wg + t * 64;    // +32 bf16 per k-tile
    char* la = smc + buf * 16384 + w * 4096;
    char* lw = smc + 32768 + buf * 8192 + w * 2048;
#pragma unroll
    for (int i = 0; i < 4; ++i) gld_lds16(at + aoff[i], la + i * 1024);
#pragma unroll
    for (int j = 0; j < 2; ++j) gld_lds16(wt + woff[j], lw + j * 1024);
  };

  stage(0, 0);
  stage(1, 1);

  for (int kt = 0; kt < 32; ++kt) {
    asm volatile("s_waitcnt vmcnt(6)" ::: "memory");  // tile kt landed; kt+1 in flight
    __builtin_amdgcn_s_barrier();
    const char* Ab = smc + (kt & 1) * 16384 + w * 4096;
    const char* Wb = smc + 32768 + (kt & 1) * 8192;
#pragma unroll
    for (int db = 0; db < 2; ++db) {
      const int s0 = db * 4 + 2 * h;
      uint4 u0 = *(const uint4*)(Ab + l31 * 128 + ((s0 ^ asw) << 4));
      uint4 u1 = *(const uint4*)(Ab + l31 * 128 + (((s0 + 1) ^ asw) << 4));
      float4 a0 = __builtin_bit_cast(float4, u0);
      float4 a1 = __builtin_bit_cast(float4, u1);
      bf16x8 af;
      af[0] = (bf16_t)a0.x; af[1] = (bf16_t)a0.y; af[2] = (bf16_t)a0.z; af[3] = (bf16_t)a0.w;
      af[4] = (bf16_t)a1.x; af[5] = (bf16_t)a1.y; af[6] = (bf16_t)a1.z; af[7] = (bf16_t)a1.w;
      const int ws = 2 * db + h;
#pragma unroll
      for (int nf = 0; nf < 4; ++nf) {
        int n = nf * 32 + l31;
        bf16x8 wf = *(const bf16x8*)(Wb + n * 64 + ((ws ^ ((n >> 1) & 3)) << 4));
        acc[nf] = mfma32(af, wf, acc[nf]);
      }
    }
    __builtin_amdgcn_s_barrier();
    stage((kt + 2) & 31, kt & 1);  // wrap keeps vmcnt count uniform
  }
  asm volatile("s_waitcnt vmcnt(0)" ::: "memory");  // drain wrap loads
  __syncthreads();                                  // epilogue reuses smc

  if (ty < 2) {
    // Stage C-tile in LDS (row stride 264B vs bank aliasing), then coalesced uint4 out.
    constexpr int RS = 264;
#pragma unroll
    for (int nf = 0; nf < 4; ++nf)
#pragma unroll
      for (int r = 0; r < 16; ++r) {
        int rowL = w * 32 + (r & 3) + 8 * (r >> 2) + 4 * h;
        *(bf16_t*)(smc + rowL * RS + (nf * 32 + l31) * 2) = (bf16_t)acc[nf][r];
      }
    __syncthreads();
    bf16_t* O = (ty == 0) ? Qp : Kp;
    char* obase = (char*)(O + (size_t)(bm * 128) * 128);
#pragma unroll
    for (int ii = 0; ii < 8; ++ii) {
      int g = ii * 256 + tid;          // 2048 x 16B chunks
      int rr = g >> 4, ch = g & 15;
      uint4 vv = *(const uint4*)(smc + rr * RS + ch * 16);
      *(uint4*)(obase + rr * 256 + ch * 16) = vv;
    }
  } else {
    // transpose 128x128 tile through LDS, write Vt[b][n][m] coalesced
#pragma unroll
    for (int nf = 0; nf < 4; ++nf)
#pragma unroll
      for (int rg = 0; rg < 4; ++rg) {
        int n = nf * 32 + l31;
        bf16x4v bv;
#pragma unroll
        for (int j = 0; j < 4; ++j) bv[j] = (bf16_t)acc[nf][rg * 4 + j];
        int byt = n * 256 + (((4 * w + rg) ^ (n & 7)) << 4) + 8 * h;
        *(uint2*)(smc + byt) = __builtin_bit_cast(uint2, bv);
      }
    __syncthreads();
    const int bb = bm >> 5;
    const int r0v = (bm & 31) * 128;
#pragma unroll
    for (int i = 0; i < 8; ++i) {
      int c = tid + 256 * i;
      int n = c >> 4, sl = c & 15;
      uint4 vv = *(const uint4*)(smc + n * 256 + ((sl ^ (n & 7)) << 4));
      *(uint4*)(Vt + (size_t)(bb * 128 + n) * 4096 + r0v + sl * 8) = vv;
    }
  }
}

// Build PV A-fragment (j = B0-half of one f32x16 S block, 16 j's) in-register:
// 4x v_cvt_pk_bf16_f32 + 4x shfl_xor(32) + selects. No LDS.
template <int B0>
static __device__ __forceinline__ bf16x8 build_pf(const f32x16& s, int h) {
  unsigned c0, c1, c2, c3;
  asm("v_cvt_pk_bf16_f32 %0, %1, %2" : "=v"(c0) : "v"(s[B0 + 0]), "v"(s[B0 + 1]));
  asm("v_cvt_pk_bf16_f32 %0, %1, %2" : "=v"(c1) : "v"(s[B0 + 2]), "v"(s[B0 + 3]));
  asm("v_cvt_pk_bf16_f32 %0, %1, %2" : "=v"(c2) : "v"(s[B0 + 4]), "v"(s[B0 + 5]));
  asm("v_cvt_pk_bf16_f32 %0, %1, %2" : "=v"(c3) : "v"(s[B0 + 6]), "v"(s[B0 + 7]));
  unsigned x0 = (unsigned)__shfl_xor((int)c0, 32);
  unsigned x1 = (unsigned)__shfl_xor((int)c1, 32);
  unsigned x2 = (unsigned)__shfl_xor((int)c2, 32);
  unsigned x3 = (unsigned)__shfl_xor((int)c3, 32);
  uint4 u;
  u.x = h ? x2 : c0;
  u.y = h ? x3 : c1;
  u.z = h ? c2 : x0;
  u.w = h ? c3 : x1;
  return __builtin_bit_cast(bf16x8, u);
}

// Flash attention. 256 threads (4 waves), QBLK=128 (32 q-rows/wave), KVBLK=64.
// K/V double-buffered in LDS via global_load_lds with gather-side swizzle;
// counted vmcnt(8) pipeline (never 0 in main loop).
// grid.x = 256*SPLIT: b = bid&7 (XCD affinity), qt = (bid>>3)&31, s = bid>>8.
template <int SPLIT>
__global__ __launch_bounds__(256, 2) void attn_kernel(
    const bf16_t* __restrict__ Qp, const bf16_t* __restrict__ Kp,
    const bf16_t* __restrict__ Vt, float* __restrict__ out,
    float* __restrict__ Opart, float* __restrict__ Mpart, float* __restrict__ Lpart) {
  __shared__ __align__(16) char smc[65536];  // 2 x (K 16K | V 16K)
  const int tid = threadIdx.x;
  const int lane = tid & 63, w = tid >> 6;
  const int l31 = lane & 31, h = lane >> 5;
  const int bid = blockIdx.x;
  const int b = bid & 7;
  const int qt = (bid >> 3) & 31;
  const int s = bid >> 8;
  const int NT = 64 / SPLIT;
  const float CEXP = CEXP_CONST;
  const int qbase = qt * 128 + w * 32;
  const int sw0 = (l31 ^ (l31 >> 3)) & 7;  // K-row swizzle for row l31
  const int sw1 = sw0 ^ 4;                 // for row l31+32

  // Q fragments: lane holds q-row l31, d = db*16 + h*8 + 0..8
  bf16x8 qf[8];
  const bf16_t* qrow = Qp + (size_t)(b * 4096 + qbase + l31) * 128 + h * 8;
#pragma unroll
  for (int db = 0; db < 8; ++db) qf[db] = *(const bf16x8*)(qrow + db * 16);

  // V-row swizzle for rows d = nf*32 + l31
  int swv[4];
#pragma unroll
  for (int nf = 0; nf < 4; ++nf) swv[nf] = (l31 & 7) ^ ((4 * nf + (l31 >> 3)) & 7);

  // Gather offsets (swizzle on the global side; LDS dest linear).
  const int rl = lane >> 4, slK = lane & 15;
  const int dl = lane >> 3, slV = lane & 7;
  int koff[4], voff[4];
#pragma unroll
  for (int i = 0; i < 4; ++i) {
    int r = w * 16 + i * 4 + rl;
    int swr = (r ^ (r >> 3)) & 7;
    koff[i] = r * 256 + (((slK & 8) | ((slK & 7) ^ swr)) << 4);
    int d = w * 32 + i * 8 + dl;
    int swd = (d ^ (d >> 3)) & 7;
    voff[i] = d * 8192 + ((slV ^ swd) << 4);
  }
  const char* kpb = (const char*)Kp + (size_t)b * 1048576 + (size_t)s * NT * 16384;
  const char* vpb = (const char*)Vt + (size_t)b * 1048576 + (size_t)s * NT * 128;

  f32x16 oacc[4];
#pragma unroll
  for (int nf = 0; nf < 4; ++nf)
#pragma unroll
    for (int r = 0; r < 16; ++r) oacc[nf][r] = 0.0f;
  float m_run = -3.0e38f, lacc = 0.0f;

  auto stage = [&](int tt, int bufb) {
    const char* kb = kpb + (size_t)tt * 16384;
    const char* vb = vpb + (size_t)tt * 128;
    char* lk = smc + bufb + w * 4096;
    char* lv = smc + bufb + 16384 + w * 4096;
#pragma unroll
    for (int i = 0; i < 4; ++i) {
      gld_lds16(kb + koff[i], lk + i * 1024);
      gld_lds16(vb + voff[i], lv + i * 1024);
    }
  };

  stage(0, 0);
  stage(1, 32768);

  for (int t = 0; t < NT; ++t) {
    asm volatile("s_waitcnt vmcnt(8)" ::: "memory");  // tile t landed; t+1 in flight
    __builtin_amdgcn_s_barrier();
    const char* kb = smc + (t & 1) * 32768;
    const char* vb = kb + 16384;

    // ---- S^T = mfma(K, Q): lane owns q-row l31 ----
    f32x16 s0, s1;
#pragma unroll
    for (int i = 0; i < 16; ++i) { s0[i] = 0.0f; s1[i] = 0.0f; }
    __builtin_amdgcn_s_setprio(1);
#pragma unroll
    for (int db = 0; db < 8; ++db) {
      const int q = 2 * db + h;
      bf16x8 k0 = *(const bf16x8*)(kb + l31 * 256 + (((q & 8) | ((q & 7) ^ sw0)) << 4));
      bf16x8 k1 = *(const bf16x8*)(kb + (32 + l31) * 256 + (((q & 8) | ((q & 7) ^ sw1)) << 4));
      s0 = mfma32(k0, qf[db], s0);
      s1 = mfma32(k1, qf[db], s1);
    }
    __builtin_amdgcn_s_setprio(0);

    // ---- online softmax (raw logits; scale folded into exp2) ----
    float tmax = fmaxf(s0[0], s1[0]);
#pragma unroll
    for (int i = 1; i < 16; ++i) tmax = fmaxf(tmax, fmaxf(s0[i], s1[i]));
    tmax = fmaxf(tmax, __shfl_xor(tmax, 32));
    if (__any(tmax > m_run + 62.0f)) {  // defer-max: p bounded by 2^7.9
      float mnew = fmaxf(m_run, tmax);
      float fac = exp2f((m_run - mnew) * CEXP);
      m_run = mnew;
      lacc *= fac;
#pragma unroll
      for (int r = 0; r < 16; ++r) {
        float fr = __shfl(fac, (r & 3) + 8 * (r >> 2) + 4 * h);
#pragma unroll
        for (int nf = 0; nf < 4; ++nf) oacc[nf][r] *= fr;
      }
    }
    const float mc = m_run * CEXP;
#pragma unroll
    for (int i = 0; i < 16; ++i) s0[i] = exp2f(fmaf(s0[i], CEXP, -mc));
#pragma unroll
    for (int i = 0; i < 16; ++i) s1[i] = exp2f(fmaf(s1[i], CEXP, -mc));
    float a0 = 0.f, a1 = 0.f, a2 = 0.f, a3 = 0.f;
#pragma unroll
    for (int i = 0; i < 16; i += 4) {
      a0 += s0[i] + s1[i];         a1 += s0[i + 1] + s1[i + 1];
      a2 += s0[i + 2] + s1[i + 2]; a3 += s0[i + 3] + s1[i + 3];
    }
    lacc += (a0 + a1) + (a2 + a3);

    // ---- PV: oacc += P[32q x 64j] @ V[64j x 128d], P built in-register ----
    __builtin_amdgcn_s_setprio(1);
    {
      bf16x8 pf = build_pf<0>(s0, h);
#pragma unroll
      for (int nf = 0; nf < 4; ++nf) {
        bf16x8 vf = *(const bf16x8*)(vb + (nf * 32 + l31) * 128 + (((0 + h) ^ swv[nf]) << 4));
        oacc[nf] = mfma32(pf, vf, oacc[nf]);
      }
    }
    {
      bf16x8 pf = build_pf<8>(s0, h);
#pragma unroll
      for (int nf = 0; nf < 4; ++nf) {
        bf16x8 vf = *(const bf16x8*)(vb + (nf * 32 + l31) * 128 + (((2 + h) ^ swv[nf]) << 4));
        oacc[nf] = mfma32(pf, vf, oacc[nf]);
      }
    }
    {
      bf16x8 pf = build_pf<0>(s1, h);
#pragma unroll
      for (int nf = 0; nf < 4; ++nf) {
        bf16x8 vf = *(const bf16x8*)(vb + (nf * 32 + l31) * 128 + (((4 + h) ^ swv[nf]) << 4));
        oacc[nf] = mfma32(pf, vf, oacc[nf]);
      }
    }
    {
      bf16x8 pf = build_pf<8>(s1, h);
#pragma unroll
      for (int nf = 0; nf < 4; ++nf) {
        bf16x8 vf = *(const bf16x8*)(vb + (nf * 32 + l31) * 128 + (((6 + h) ^ swv[nf]) << 4));
        oacc[nf] = mfma32(pf, vf, oacc[nf]);
      }
    }
    __builtin_amdgcn_s_setprio(0);

    __builtin_amdgcn_s_barrier();  // all waves done reading buf[t&1]
    stage((t + 2) & (NT - 1), (t & 1) * 32768);  // wrap keeps vmcnt count uniform
  }
  asm volatile("s_waitcnt vmcnt(0)" ::: "memory");  // drain wrap loads

  lacc += __shfl_xor(lacc, 32);
  if (SPLIT == 1) {
    const float inv = 1.0f / lacc;
    float* ob = out + (size_t)(b * 4096 + qbase) * 128;
#pragma unroll
    for (int r = 0; r < 16; ++r) {
      const int rowD = (r & 3) + 8 * (r >> 2) + 4 * h;
      float ir = __shfl(inv, rowD);
#pragma unroll
      for (int nf = 0; nf < 4; ++nf)
        ob[(size_t)rowD * 128 + nf * 32 + l31] = oacc[nf][r] * ir;
    }
  } else {
    const int pb = s * 256 + b * 32 + qt;
    if (lane < 32) {
      Mpart[pb * 128 + w * 32 + l31] = m_run;
      Lpart[pb * 128 + w * 32 + l31] = lacc;
    }
    float* ob = Opart + ((size_t)pb * 128 + w * 32) * 128;
#pragma unroll
    for (int r = 0; r < 16; ++r) {
      const int rowD = (r & 3) + 8 * (r >> 2) + 4 * h;
#pragma unroll
      for (int nf = 0; nf < 4; ++nf)
        ob[(size_t)rowD * 128 + nf * 32 + l31] = oacc[nf][r];
    }
  }
}

// Combine 2 split partials. grid 4096 x 256: 8 rows/block, 32 lanes/row (float4).
__global__ __launch_bounds__(256) void combine_kernel(
    const float* __restrict__ Opart, const float* __restrict__ Mpart,
    const float* __restrict__ Lpart, float* __restrict__ out) {
  const int g = blockIdx.x * 8 + (threadIdx.x >> 5);  // global q-row, 0..32767
  const int lane32 = threadIdx.x & 31;
  const int b = g >> 12;
  const int pos = g & 4095;
  const int qt = pos >> 7;
  const int row = pos & 127;
  const int i0 = (b * 32 + qt) * 128 + row;
  const int i1 = (256 + b * 32 + qt) * 128 + row;
  const float m0 = Mpart[i0], m1 = Mpart[i1];
  const float l0 = Lpart[i0], l1 = Lpart[i1];
  const float m = fmaxf(m0, m1);
  const float w0 = exp2f((m0 - m) * CEXP_CONST);
  const float w1 = exp2f((m1 - m) * CEXP_CONST);
  const float inv = 1.0f / (w0 * l0 + w1 * l1);
  const float4 o0 = *(const float4*)(Opart + (size_t)i0 * 128 + lane32 * 4);
  const float4 o1 = *(const float4*)(Opart + (size_t)i1 * 128 + lane32 * 4);
  float4 o;
  o.x = (w0 * o0.x + w1 * o1.x) * inv;
  o.y = (w0 * o0.y + w1 * o1.y) * inv;
  o.z = (w0 * o0.z + w1 * o1.z) * inv;
  o.w = (w0 * o0.w + w1 * o1.w) * inv;
  *(float4*)(out + (size_t)g * 128 + lane32 * 4) = o;
}

extern "C" void kernel_launch(void* const* d_in, const int* in_sizes, int n_in,
                              void* d_out, int out_size, void* d_ws, size_t ws_size,
                              hipStream_t stream) {
  const float* q  = (const float*)d_in[0];
  const float* k  = (const float*)d_in[1];
  const float* v  = (const float*)d_in[2];
  const float* Wq = (const float*)d_in[3];
  const float* Wk = (const float*)d_in[4];
  const float* Wv = (const float*)d_in[5];
  float* out = (float*)d_out;
  char* ws = (char*)d_ws;
  bf16_t* Wt = (bf16_t*)(ws);
  bf16_t* Qp = (bf16_t*)(ws + (size_t)(1u << 20));
  bf16_t* Kp = (bf16_t*)(ws + (size_t)(9u << 20));
  bf16_t* Vt = (bf16_t*)(ws + (size_t)(17u << 20));
  float* Opart = (float*)(ws + (size_t)(32u << 20));
  float* Mpart = (float*)(ws + (size_t)(64u << 20));
  float* Lpart = (float*)(ws + (size_t)(64u << 20) + (256u << 10));

  hipLaunchKernelGGL(wt_kernel, dim3(1536), dim3(256), 0, stream, Wq, Wk, Wv, Wt);
  hipLaunchKernelGGL(proj_kernel, dim3(256, 3), dim3(256), 0, stream, q, k, v, Wt, Qp, Kp, Vt);

  if (ws_size >= ((size_t)65 << 20)) {
    hipLaunchKernelGGL((attn_kernel<2>), dim3(512), dim3(256), 0, stream,
                       Qp, Kp, Vt, out, Opart, Mpart, Lpart);
    hipLaunchKernelGGL(combine_kernel, dim3(4096), dim3(256), 0, stream,
                       Opart, Mpart, Lpart, out);
  } else {
    hipLaunchKernelGGL((attn_kernel<1>), dim3(256), dim3(256), 0, stream,
                       Qp, Kp, Vt, out, Opart, Mpart, Lpart);
  }
}